// Round 1
// baseline (1145.202 us; speedup 1.0000x reference)
//
#include <hip/hip_runtime.h>
#include <math.h>

#define INV_TAU 1000.0f   // 1/TAU, TAU=0.001
#define TEMP    0.1f

// Problem constants: B=2,H=8 -> BH=16; N=256; L=64
// X,Y: [BH, 256, 64] fp32.  out: [BH, 256, 256] fp32.
//
// ws layout (floats):
//   cost  [16][256][256]  off 0         size 1048576
//   srtu  [16][64][256]   off 1048576   size 262144   (descending-sorted X col)
//   ziu   [16][64][256]   off 1310720   size 262144   (1/Z row normalizers)
//   srtv  [16][64][256]   off 1572864   size 262144
//   ziv   [16][64][256]   off 1835008   size 262144
//   swds  [16][64]        off 2097152   size 1024
//   wts   [16][64]        off 2098176   size 1024
// total 2,099,200 floats = 8.4 MB

__device__ __forceinline__ void bitonic_sort_asc256(float* s, int tid) {
  // standard bitonic network, 256 elems, 256 threads, ascending
  for (int k = 2; k <= 256; k <<= 1) {
    for (int j = k >> 1; j > 0; j >>= 1) {
      __syncthreads();
      int ixj = tid ^ j;
      if (ixj > tid) {
        float a = s[tid], b = s[ixj];
        bool up = ((tid & k) == 0);
        if (up ? (a > b) : (a < b)) { s[tid] = b; s[ixj] = a; }
      }
    }
  }
  __syncthreads();
}

// K1: cost[bh][j][k] = sqrt(max(|Xj|^2 + |Yk|^2 - 2 Xj.Yk, 1e-12))
__global__ __launch_bounds__(256) void cost_kernel(const float* __restrict__ X,
                                                   const float* __restrict__ Y,
                                                   float* __restrict__ cost) {
  const int j = blockIdx.x, bh = blockIdx.y, k = threadIdx.x;
  __shared__ float xr[64];
  if (k < 64) xr[k] = X[((size_t)bh*256 + j)*64 + k];
  __syncthreads();
  const float4* yp = (const float4*)(Y + ((size_t)bh*256 + k)*64);
  const float4* xp = (const float4*)xr;
  float dot = 0.f, x2 = 0.f, y2 = 0.f;
#pragma unroll
  for (int t = 0; t < 16; ++t) {
    float4 yv = yp[t], xv = xp[t];
    dot += xv.x*yv.x + xv.y*yv.y + xv.z*yv.z + xv.w*yv.w;
    x2  += xv.x*xv.x + xv.y*xv.y + xv.z*xv.z + xv.w*xv.w;
    y2  += yv.x*yv.x + yv.y*yv.y + yv.z*yv.z + yv.w*yv.w;
  }
  float c = x2 + y2 - 2.f*dot;
  cost[((size_t)bh*256 + j)*256 + k] = sqrtf(fmaxf(c, 1e-12f));
}

// K2: per (bh,l): descending sort of X/Y column, and 1/Z per sorted row.
// Row max of logits is exactly 0 (srt_i is one of the s_j), so Z = sum exp(pd).
__global__ __launch_bounds__(256) void sortz_kernel(const float* __restrict__ X,
                                                    const float* __restrict__ Y,
                                                    float* __restrict__ srtu, float* __restrict__ ziu,
                                                    float* __restrict__ srtv, float* __restrict__ ziv) {
  const int l = blockIdx.x, bh = blockIdx.y, tid = threadIdx.x;
  __shared__ float s[256];
  const int base = (bh*64 + l)*256 + tid;

  s[tid] = X[((size_t)bh*256 + tid)*64 + l];
  bitonic_sort_asc256(s, tid);
  float v = s[255 - tid];           // descending
  float z = 0.f;
  for (int jj = 0; jj < 256; ++jj) { float d = s[jj] - v; z += __expf(-d*d*INV_TAU); }
  srtu[base] = v; ziu[base] = 1.0f / z;
  __syncthreads();

  s[tid] = Y[((size_t)bh*256 + tid)*64 + l];
  bitonic_sort_asc256(s, tid);
  v = s[255 - tid];
  z = 0.f;
  for (int jj = 0; jj < 256; ++jj) { float d = s[jj] - v; z += __expf(-d*d*INV_TAU); }
  srtv[base] = v; ziv[base] = 1.0f / z;
}

// K3: swds[bh][l] = sum_i sum_k (sum_j Pu[i,j] cost[j,k]) * Pv[i,k]
// Block = (bh,l), 256 thr: tx=tid&63 covers k in float4 chunks, ty=tid>>6 covers
// 4 of 16 i's per i-tile.  Pu tile staged in LDS as PUT[j][ii] (padded row 20).
__global__ __launch_bounds__(256) void swds_kernel(const float* __restrict__ X,
                                                   const float* __restrict__ Y,
                                                   const float* __restrict__ cost,
                                                   const float* __restrict__ srtu, const float* __restrict__ ziu,
                                                   const float* __restrict__ srtv, const float* __restrict__ ziv,
                                                   float* __restrict__ swds) {
  const int l = blockIdx.x, bh = blockIdx.y, tid = threadIdx.x;
  const int tx = tid & 63, ty = tid >> 6;
  __shared__ float ssu[256], ssv[256], ssrtu[256], szu[256], ssrtv[256], szv[256];
  __shared__ float PUT[256][20];   // [j][ii], padded to keep 16B alignment + spread banks
  __shared__ float red[4];
  const int lb = (bh*64 + l)*256;
  ssu[tid]   = X[((size_t)bh*256 + tid)*64 + l];
  ssv[tid]   = Y[((size_t)bh*256 + tid)*64 + l];
  ssrtu[tid] = srtu[lb + tid]; szu[tid] = ziu[lb + tid];
  ssrtv[tid] = srtv[lb + tid]; szv[tid] = ziv[lb + tid];
  __syncthreads();

  const float* cb = cost + (size_t)bh * 65536;
  float sv4[4];
#pragma unroll
  for (int b = 0; b < 4; ++b) sv4[b] = ssv[tx*4 + b];

  float part = 0.f;
  for (int it = 0; it < 16; ++it) {
    const int i0 = it * 16;
    // stage Pu rows i0..i0+15, transposed: PUT[j=tid][ii]
    {
      float sj = ssu[tid];
#pragma unroll
      for (int r = 0; r < 16; ++r) {
        float d = sj - ssrtu[i0 + r];
        PUT[tid][r] = __expf(-d*d*INV_TAU) * szu[i0 + r];
      }
    }
    __syncthreads();
    float mac[4][4] = {{0.f,0.f,0.f,0.f},{0.f,0.f,0.f,0.f},{0.f,0.f,0.f,0.f},{0.f,0.f,0.f,0.f}};
#pragma unroll 4
    for (int j = 0; j < 256; ++j) {
      float4 pu = *(const float4*)&PUT[j][ty*4];                    // LDS broadcast
      float4 c  = *(const float4*)&cb[(size_t)j*256 + tx*4];        // coalesced, L1/L2-hot
      mac[0][0] += pu.x*c.x; mac[0][1] += pu.x*c.y; mac[0][2] += pu.x*c.z; mac[0][3] += pu.x*c.w;
      mac[1][0] += pu.y*c.x; mac[1][1] += pu.y*c.y; mac[1][2] += pu.y*c.z; mac[1][3] += pu.y*c.w;
      mac[2][0] += pu.z*c.x; mac[2][1] += pu.z*c.y; mac[2][2] += pu.z*c.z; mac[2][3] += pu.z*c.w;
      mac[3][0] += pu.w*c.x; mac[3][1] += pu.w*c.y; mac[3][2] += pu.w*c.z; mac[3][3] += pu.w*c.w;
    }
#pragma unroll
    for (int a = 0; a < 4; ++a) {
      const int i = i0 + ty*4 + a;
      float sr = ssrtv[i], zi = szv[i];
#pragma unroll
      for (int b = 0; b < 4; ++b) {
        float d = sv4[b] - sr;
        part += mac[a][b] * (__expf(-d*d*INV_TAU) * zi);
      }
    }
    __syncthreads();
  }
  // block reduce
#pragma unroll
  for (int o = 32; o > 0; o >>= 1) part += __shfl_down(part, o, 64);
  if (tx == 0) red[ty] = part;
  __syncthreads();
  if (tid == 0) swds[bh*64 + l] = red[0] + red[1] + red[2] + red[3];
}

// K4: weights = softmax(-TEMP * swds) over l (one wave per bh)
__global__ void weights_kernel(const float* __restrict__ swds, float* __restrict__ weights) {
  const int bh = blockIdx.x, t = threadIdx.x;
  float v = -TEMP * swds[bh*64 + t];
  float m = v;
#pragma unroll
  for (int o = 32; o > 0; o >>= 1) m = fmaxf(m, __shfl_xor(m, o, 64));
  float e = __expf(v - m);
  float ssum = e;
#pragma unroll
  for (int o = 32; o > 0; o >>= 1) ssum += __shfl_xor(ssum, o, 64);
  weights[bh*64 + t] = e / ssum;
}

// K5: out[bh][j][k] += sum_l w_l sum_i Pu_l[i,j] Pv_l[i,k]
// Block = (64x64 out tile, group of 16 l's, bh).  w folded into Pu normalizer.
// Outer-product accumulation with 4x4 per-thread register tile; atomicAdd epilogue.
__global__ __launch_bounds__(256) void out_kernel(const float* __restrict__ X,
                                                  const float* __restrict__ Y,
                                                  const float* __restrict__ srtu, const float* __restrict__ ziu,
                                                  const float* __restrict__ srtv, const float* __restrict__ ziv,
                                                  const float* __restrict__ weights,
                                                  float* __restrict__ out) {
  const int bh = blockIdx.z;
  const int jt = blockIdx.x >> 2, kt = blockIdx.x & 3;
  const int j0 = jt * 64, k0 = kt * 64;
  const int tid = threadIdx.x;
  __shared__ float ssrtu[256], szu[256], ssrtv[256], szv[256];
  __shared__ float sut[64], svt[64];
  __shared__ float EU[16][64], EV[16][64];
  const int sii = tid >> 4;          // staging: which i within tile
  const int sjj = (tid & 15) * 4;    // staging: which 4 cols
  const int jj4 = (tid >> 4) * 4;    // compute: 4 j's
  const int kk4 = (tid & 15) * 4;    // compute: 4 k's
  float acc[4][4] = {{0.f,0.f,0.f,0.f},{0.f,0.f,0.f,0.f},{0.f,0.f,0.f,0.f},{0.f,0.f,0.f,0.f}};

  for (int lg = 0; lg < 16; ++lg) {
    const int l = blockIdx.y * 16 + lg;
    const int lb = (bh*64 + l)*256;
    const float w = weights[bh*64 + l];
    __syncthreads();                 // previous iter's LDS readers done
    ssrtu[tid] = srtu[lb + tid];
    szu[tid]   = ziu[lb + tid] * w;  // fold weight into Pu normalizer
    ssrtv[tid] = srtv[lb + tid];
    szv[tid]   = ziv[lb + tid];
    if (tid < 64)       sut[tid]      = X[((size_t)bh*256 + j0 + tid)*64 + l];
    else if (tid < 128) svt[tid - 64] = Y[((size_t)bh*256 + k0 + (tid - 64))*64 + l];
    __syncthreads();

    for (int it = 0; it < 16; ++it) {
      const int i0 = it * 16;
      {
        float sru = ssrtu[i0 + sii], zu = szu[i0 + sii];
        float4 e; float d;
        d = sut[sjj+0] - sru; e.x = __expf(-d*d*INV_TAU) * zu;
        d = sut[sjj+1] - sru; e.y = __expf(-d*d*INV_TAU) * zu;
        d = sut[sjj+2] - sru; e.z = __expf(-d*d*INV_TAU) * zu;
        d = sut[sjj+3] - sru; e.w = __expf(-d*d*INV_TAU) * zu;
        *(float4*)&EU[sii][sjj] = e;
        float srv = ssrtv[i0 + sii], zv = szv[i0 + sii];
        d = svt[sjj+0] - srv; e.x = __expf(-d*d*INV_TAU) * zv;
        d = svt[sjj+1] - srv; e.y = __expf(-d*d*INV_TAU) * zv;
        d = svt[sjj+2] - srv; e.z = __expf(-d*d*INV_TAU) * zv;
        d = svt[sjj+3] - srv; e.w = __expf(-d*d*INV_TAU) * zv;
        *(float4*)&EV[sii][sjj] = e;
      }
      __syncthreads();
#pragma unroll
      for (int ii = 0; ii < 16; ++ii) {
        float4 a = *(const float4*)&EU[ii][jj4];
        float4 b = *(const float4*)&EV[ii][kk4];
        acc[0][0] += a.x*b.x; acc[0][1] += a.x*b.y; acc[0][2] += a.x*b.z; acc[0][3] += a.x*b.w;
        acc[1][0] += a.y*b.x; acc[1][1] += a.y*b.y; acc[1][2] += a.y*b.z; acc[1][3] += a.y*b.w;
        acc[2][0] += a.z*b.x; acc[2][1] += a.z*b.y; acc[2][2] += a.z*b.z; acc[2][3] += a.z*b.w;
        acc[3][0] += a.w*b.x; acc[3][1] += a.w*b.y; acc[3][2] += a.w*b.z; acc[3][3] += a.w*b.w;
      }
      __syncthreads();
    }
  }
  float* ob = out + ((size_t)bh*256 + j0 + jj4)*256 + k0 + kk4;
#pragma unroll
  for (int r = 0; r < 4; ++r) {
#pragma unroll
    for (int c = 0; c < 4; ++c) atomicAdd(&ob[r*256 + c], acc[r][c]);
  }
}

extern "C" void kernel_launch(void* const* d_in, const int* in_sizes, int n_in,
                              void* d_out, int out_size, void* d_ws, size_t ws_size,
                              hipStream_t stream) {
  (void)in_sizes; (void)n_in; (void)ws_size;
  const float* X = (const float*)d_in[0];
  const float* Y = (const float*)d_in[1];
  float* out = (float*)d_out;
  float* ws  = (float*)d_ws;
  float* cost = ws;                   // 1048576
  float* srtu = ws  + 1048576;        // 262144
  float* ziu  = srtu + 262144;
  float* srtv = ziu  + 262144;
  float* ziv  = srtv + 262144;
  float* swds = ziv  + 262144;        // 1024
  float* wts  = swds + 1024;          // 1024

  hipMemsetAsync(d_out, 0, (size_t)out_size * sizeof(float), stream);
  cost_kernel   <<<dim3(256, 16), 256, 0, stream>>>(X, Y, cost);
  sortz_kernel  <<<dim3(64, 16),  256, 0, stream>>>(X, Y, srtu, ziu, srtv, ziv);
  swds_kernel   <<<dim3(64, 16),  256, 0, stream>>>(X, Y, cost, srtu, ziu, srtv, ziv, swds);
  weights_kernel<<<dim3(16),       64, 0, stream>>>(swds, wts);
  out_kernel    <<<dim3(16, 4, 16), 256, 0, stream>>>(X, Y, srtu, ziu, srtv, ziv, wts, out);
}

// Round 2
// 987.754 us; speedup vs baseline: 1.1594x; 1.1594x over previous
//
#include <hip/hip_runtime.h>
#include <math.h>

#define INV_TAU 1000.0f   // 1/TAU, TAU=0.001
#define TEMP    0.1f

// Problem constants: B=2,H=8 -> BH=16; N=256; L=64
// X,Y: [BH, 256, 64] fp32.  out: [BH, 256, 256] fp32.
//
// ws layout (floats):
//   cost  [16][256][256]  off 0         size 1048576
//   srtu  [16][64][256]   off 1048576   size 262144   (descending-sorted X col)
//   ziu   [16][64][256]   off 1310720   size 262144   (1/Z row normalizers)
//   srtv  [16][64][256]   off 1572864   size 262144
//   ziv   [16][64][256]   off 1835008   size 262144
//   swds  [16][64]        off 2097152   size 1024
//   wts   [16][64]        off 2098176   size 1024
//   gamma [16][64][256][256] off 2099200 size 67108864  (Path A only, 256 MiB)

__device__ __forceinline__ void bitonic_sort_asc256(float* s, int tid) {
  for (int k = 2; k <= 256; k <<= 1) {
    for (int j = k >> 1; j > 0; j >>= 1) {
      __syncthreads();
      int ixj = tid ^ j;
      if (ixj > tid) {
        float a = s[tid], b = s[ixj];
        bool up = ((tid & k) == 0);
        if (up ? (a > b) : (a < b)) { s[tid] = b; s[ixj] = a; }
      }
    }
  }
  __syncthreads();
}

// K1: cost[bh][j][k] = sqrt(max(|Xj|^2 + |Yk|^2 - 2 Xj.Yk, 1e-12))
__global__ __launch_bounds__(256) void cost_kernel(const float* __restrict__ X,
                                                   const float* __restrict__ Y,
                                                   float* __restrict__ cost) {
  const int j = blockIdx.x, bh = blockIdx.y, k = threadIdx.x;
  __shared__ __align__(16) float xr[64];
  if (k < 64) xr[k] = X[((size_t)bh*256 + j)*64 + k];
  __syncthreads();
  const float4* yp = (const float4*)(Y + ((size_t)bh*256 + k)*64);
  const float4* xp = (const float4*)xr;
  float dot = 0.f, x2 = 0.f, y2 = 0.f;
#pragma unroll
  for (int t = 0; t < 16; ++t) {
    float4 yv = yp[t], xv = xp[t];
    dot += xv.x*yv.x + xv.y*yv.y + xv.z*yv.z + xv.w*yv.w;
    x2  += xv.x*xv.x + xv.y*xv.y + xv.z*xv.z + xv.w*xv.w;
    y2  += yv.x*yv.x + yv.y*yv.y + yv.z*yv.z + yv.w*yv.w;
  }
  float c = x2 + y2 - 2.f*dot;
  cost[((size_t)bh*256 + j)*256 + k] = sqrtf(fmaxf(c, 1e-12f));
}

// K2: per (bh,l): descending sort of X/Y column, and 1/Z per sorted row.
// Row max of logits is exactly 0 (srt_i is one of the s_j), so Z = sum exp(pd).
__global__ __launch_bounds__(256) void sortz_kernel(const float* __restrict__ X,
                                                    const float* __restrict__ Y,
                                                    float* __restrict__ srtu, float* __restrict__ ziu,
                                                    float* __restrict__ srtv, float* __restrict__ ziv) {
  const int l = blockIdx.x, bh = blockIdx.y, tid = threadIdx.x;
  __shared__ float s[256];
  const int base = (bh*64 + l)*256 + tid;

  s[tid] = X[((size_t)bh*256 + tid)*64 + l];
  bitonic_sort_asc256(s, tid);
  float v = s[255 - tid];           // descending
  float z = 0.f;
  for (int jj = 0; jj < 256; ++jj) { float d = s[jj] - v; z += __expf(-d*d*INV_TAU); }
  srtu[base] = v; ziu[base] = 1.0f / z;
  __syncthreads();

  s[tid] = Y[((size_t)bh*256 + tid)*64 + l];
  bitonic_sort_asc256(s, tid);
  v = s[255 - tid];
  z = 0.f;
  for (int jj = 0; jj < 256; ++jj) { float d = s[jj] - v; z += __expf(-d*d*INV_TAU); }
  srtv[base] = v; ziv[base] = 1.0f / z;
}

// K3-new: per (bh,l): compute Gamma = Pu^T Pv tile-by-tile (outer products over
// i with exp tables in LDS), dot each tile with cost (each cost elem read ONCE
// per block -> 256KB/block vs 16MB before), optionally store Gamma to ws.
// Thread (tj=tid>>4, tk=tid&15) owns 4x4 outputs in each of 4 k-tiles: acc[4][4][4].
__global__ __launch_bounds__(256) void gamma_swds_kernel(
    const float* __restrict__ X, const float* __restrict__ Y,
    const float* __restrict__ cost,
    const float* __restrict__ srtu, const float* __restrict__ ziu,
    const float* __restrict__ srtv, const float* __restrict__ ziv,
    float* __restrict__ swds, float* __restrict__ gamma, int store_gamma) {
  const int l = blockIdx.x, bh = blockIdx.y, tid = threadIdx.x;
  const int tj = tid >> 4, tk = tid & 15;
  __shared__ float ssu[256], ssv[256], ssrtu[256], szu[256], ssrtv[256], szv[256];
  __shared__ __align__(16) float EU[16][64];    // [i in chunk][j in tile]
  __shared__ __align__(16) float EV[16][260];   // [i in chunk][all 256 k], pad 260 to stagger banks
  __shared__ float red[4];
  const int lb = (bh*64 + l)*256;
  ssu[tid]   = X[((size_t)bh*256 + tid)*64 + l];
  ssv[tid]   = Y[((size_t)bh*256 + tid)*64 + l];
  ssrtu[tid] = srtu[lb + tid]; szu[tid] = ziu[lb + tid];
  ssrtv[tid] = srtv[lb + tid]; szv[tid] = ziv[lb + tid];
  __syncthreads();

  const float* cb = cost + (size_t)bh * 65536;
  float* gb = gamma + ((size_t)(bh*64 + l) << 16);
  const int si = tid >> 4;          // staging: i within chunk
  const int sc = (tid & 15) * 4;    // staging: 4 cols
  float part = 0.f;

  for (int jt = 0; jt < 4; ++jt) {
    const int j0 = jt * 64;
    float acc[4][4][4];
#pragma unroll
    for (int q = 0; q < 4; ++q)
#pragma unroll
      for (int r = 0; r < 4; ++r)
#pragma unroll
        for (int c = 0; c < 4; ++c) acc[q][r][c] = 0.f;

    for (int ic = 0; ic < 16; ++ic) {
      const int i0 = ic * 16;
      __syncthreads();               // protect LDS from previous iter's readers
      {
        float sru = ssrtu[i0 + si], zu = szu[i0 + si];
        float4 e; float d;
        d = ssu[j0+sc+0] - sru; e.x = __expf(-d*d*INV_TAU) * zu;
        d = ssu[j0+sc+1] - sru; e.y = __expf(-d*d*INV_TAU) * zu;
        d = ssu[j0+sc+2] - sru; e.z = __expf(-d*d*INV_TAU) * zu;
        d = ssu[j0+sc+3] - sru; e.w = __expf(-d*d*INV_TAU) * zu;
        *(float4*)&EU[si][sc] = e;
        float srv = ssrtv[i0 + si], zv = szv[i0 + si];
#pragma unroll
        for (int q = 0; q < 4; ++q) {
          float4 ev;
          d = ssv[q*64+sc+0] - srv; ev.x = __expf(-d*d*INV_TAU) * zv;
          d = ssv[q*64+sc+1] - srv; ev.y = __expf(-d*d*INV_TAU) * zv;
          d = ssv[q*64+sc+2] - srv; ev.z = __expf(-d*d*INV_TAU) * zv;
          d = ssv[q*64+sc+3] - srv; ev.w = __expf(-d*d*INV_TAU) * zv;
          *(float4*)&EV[si][q*64+sc] = ev;
        }
      }
      __syncthreads();
#pragma unroll
      for (int i = 0; i < 16; ++i) {
        float4 a = *(const float4*)&EU[i][tj*4];
#pragma unroll
        for (int q = 0; q < 4; ++q) {
          float4 b = *(const float4*)&EV[i][q*64 + tk*4];
          acc[q][0][0] += a.x*b.x; acc[q][0][1] += a.x*b.y; acc[q][0][2] += a.x*b.z; acc[q][0][3] += a.x*b.w;
          acc[q][1][0] += a.y*b.x; acc[q][1][1] += a.y*b.y; acc[q][1][2] += a.y*b.z; acc[q][1][3] += a.y*b.w;
          acc[q][2][0] += a.z*b.x; acc[q][2][1] += a.z*b.y; acc[q][2][2] += a.z*b.z; acc[q][2][3] += a.z*b.w;
          acc[q][3][0] += a.w*b.x; acc[q][3][1] += a.w*b.y; acc[q][3][2] += a.w*b.z; acc[q][3][3] += a.w*b.w;
        }
      }
    }
    // dot Gamma tile with cost (each cost element read exactly once) + store
#pragma unroll
    for (int q = 0; q < 4; ++q) {
#pragma unroll
      for (int r = 0; r < 4; ++r) {
        const int row = j0 + tj*4 + r;
        const int col = q*64 + tk*4;
        float4 cv = *(const float4*)&cb[(size_t)row*256 + col];
        part += acc[q][r][0]*cv.x + acc[q][r][1]*cv.y + acc[q][r][2]*cv.z + acc[q][r][3]*cv.w;
        if (store_gamma) {
          float4 g; g.x = acc[q][r][0]; g.y = acc[q][r][1]; g.z = acc[q][r][2]; g.w = acc[q][r][3];
          *(float4*)&gb[(size_t)row*256 + col] = g;
        }
      }
    }
  }
  // block reduce
#pragma unroll
  for (int o = 32; o > 0; o >>= 1) part += __shfl_down(part, o, 64);
  if ((tid & 63) == 0) red[tid >> 6] = part;
  __syncthreads();
  if (tid == 0) swds[bh*64 + l] = red[0] + red[1] + red[2] + red[3];
}

// K4: weights = softmax(-TEMP * swds) over l (one wave per bh)
__global__ void weights_kernel(const float* __restrict__ swds, float* __restrict__ weights) {
  const int bh = blockIdx.x, t = threadIdx.x;
  float v = -TEMP * swds[bh*64 + t];
  float m = v;
#pragma unroll
  for (int o = 32; o > 0; o >>= 1) m = fmaxf(m, __shfl_xor(m, o, 64));
  float e = __expf(v - m);
  float ssum = e;
#pragma unroll
  for (int o = 32; o > 0; o >>= 1) ssum += __shfl_xor(ssum, o, 64);
  weights[bh*64 + t] = e / ssum;
}

// K5-A: out = sum_l w_l * Gamma_l  (pure weighted reduction over stored Gamma)
__global__ __launch_bounds__(256) void wsum_kernel(const float* __restrict__ gamma,
                                                   const float* __restrict__ weights,
                                                   float* __restrict__ out) {
  const int bh = blockIdx.y;
  const size_t p = ((size_t)blockIdx.x * 256 + threadIdx.x) * 4;
  __shared__ float w[64];
  if (threadIdx.x < 64) w[threadIdx.x] = weights[bh*64 + threadIdx.x];
  __syncthreads();
  const float* gb = gamma + (((size_t)bh*64) << 16) + p;
  float4 acc = {0.f, 0.f, 0.f, 0.f};
#pragma unroll 4
  for (int l = 0; l < 64; ++l) {
    float4 g = *(const float4*)&gb[(size_t)l << 16];
    float wl = w[l];
    acc.x += wl*g.x; acc.y += wl*g.y; acc.z += wl*g.z; acc.w += wl*g.w;
  }
  *(float4*)&out[((size_t)bh << 16) + p] = acc;
}

// K5-B (fallback if ws too small for Gamma): recompute Gamma with w folded in.
__global__ __launch_bounds__(256) void out_kernel(const float* __restrict__ X,
                                                  const float* __restrict__ Y,
                                                  const float* __restrict__ srtu, const float* __restrict__ ziu,
                                                  const float* __restrict__ srtv, const float* __restrict__ ziv,
                                                  const float* __restrict__ weights,
                                                  float* __restrict__ out) {
  const int bh = blockIdx.z;
  const int jt = blockIdx.x >> 2, kt = blockIdx.x & 3;
  const int j0 = jt * 64, k0 = kt * 64;
  const int tid = threadIdx.x;
  __shared__ float ssrtu[256], szu[256], ssrtv[256], szv[256];
  __shared__ float sut[64], svt[64];
  __shared__ __align__(16) float EU[16][64], EV[16][64];
  const int sii = tid >> 4;
  const int sjj = (tid & 15) * 4;
  const int jj4 = (tid >> 4) * 4;
  const int kk4 = (tid & 15) * 4;
  float acc[4][4] = {{0.f,0.f,0.f,0.f},{0.f,0.f,0.f,0.f},{0.f,0.f,0.f,0.f},{0.f,0.f,0.f,0.f}};

  for (int lg = 0; lg < 16; ++lg) {
    const int l = blockIdx.y * 16 + lg;
    const int lb = (bh*64 + l)*256;
    const float w = weights[bh*64 + l];
    __syncthreads();
    ssrtu[tid] = srtu[lb + tid];
    szu[tid]   = ziu[lb + tid] * w;
    ssrtv[tid] = srtv[lb + tid];
    szv[tid]   = ziv[lb + tid];
    if (tid < 64)       sut[tid]      = X[((size_t)bh*256 + j0 + tid)*64 + l];
    else if (tid < 128) svt[tid - 64] = Y[((size_t)bh*256 + k0 + (tid - 64))*64 + l];
    __syncthreads();

    for (int it = 0; it < 16; ++it) {
      const int i0 = it * 16;
      {
        float sru = ssrtu[i0 + sii], zu = szu[i0 + sii];
        float4 e; float d;
        d = sut[sjj+0] - sru; e.x = __expf(-d*d*INV_TAU) * zu;
        d = sut[sjj+1] - sru; e.y = __expf(-d*d*INV_TAU) * zu;
        d = sut[sjj+2] - sru; e.z = __expf(-d*d*INV_TAU) * zu;
        d = sut[sjj+3] - sru; e.w = __expf(-d*d*INV_TAU) * zu;
        *(float4*)&EU[sii][sjj] = e;
        float srv = ssrtv[i0 + sii], zv = szv[i0 + sii];
        d = svt[sjj+0] - srv; e.x = __expf(-d*d*INV_TAU) * zv;
        d = svt[sjj+1] - srv; e.y = __expf(-d*d*INV_TAU) * zv;
        d = svt[sjj+2] - srv; e.z = __expf(-d*d*INV_TAU) * zv;
        d = svt[sjj+3] - srv; e.w = __expf(-d*d*INV_TAU) * zv;
        *(float4*)&EV[sii][sjj] = e;
      }
      __syncthreads();
#pragma unroll
      for (int ii = 0; ii < 16; ++ii) {
        float4 a = *(const float4*)&EU[ii][jj4];
        float4 b = *(const float4*)&EV[ii][kk4];
        acc[0][0] += a.x*b.x; acc[0][1] += a.x*b.y; acc[0][2] += a.x*b.z; acc[0][3] += a.x*b.w;
        acc[1][0] += a.y*b.x; acc[1][1] += a.y*b.y; acc[1][2] += a.y*b.z; acc[1][3] += a.y*b.w;
        acc[2][0] += a.z*b.x; acc[2][1] += a.z*b.y; acc[2][2] += a.z*b.z; acc[2][3] += a.z*b.w;
        acc[3][0] += a.w*b.x; acc[3][1] += a.w*b.y; acc[3][2] += a.w*b.z; acc[3][3] += a.w*b.w;
      }
      __syncthreads();
    }
  }
  float* ob = out + ((size_t)bh*256 + j0 + jj4)*256 + k0 + kk4;
#pragma unroll
  for (int r = 0; r < 4; ++r) {
#pragma unroll
    for (int c = 0; c < 4; ++c) atomicAdd(&ob[r*256 + c], acc[r][c]);
  }
}

extern "C" void kernel_launch(void* const* d_in, const int* in_sizes, int n_in,
                              void* d_out, int out_size, void* d_ws, size_t ws_size,
                              hipStream_t stream) {
  (void)in_sizes; (void)n_in;
  const float* X = (const float*)d_in[0];
  const float* Y = (const float*)d_in[1];
  float* out = (float*)d_out;
  float* ws  = (float*)d_ws;
  float* cost  = ws;                    // 1048576
  float* srtu  = ws   + 1048576;        // 262144
  float* ziu   = srtu + 262144;
  float* srtv  = ziu  + 262144;
  float* ziv   = srtv + 262144;
  float* swds  = ziv  + 262144;         // 1024
  float* wts   = swds + 1024;           // 1024
  float* gamma = wts  + 1024;           // 67108864 (Path A)

  const size_t need_bytes = (size_t)(2099200 + 67108864) * sizeof(float);
  const int store_gamma = (ws_size >= need_bytes) ? 1 : 0;  // constant per process -> graph-safe

  cost_kernel   <<<dim3(256, 16), 256, 0, stream>>>(X, Y, cost);
  sortz_kernel  <<<dim3(64, 16),  256, 0, stream>>>(X, Y, srtu, ziu, srtv, ziv);
  gamma_swds_kernel<<<dim3(64, 16), 256, 0, stream>>>(X, Y, cost, srtu, ziu, srtv, ziv,
                                                      swds, gamma, store_gamma);
  weights_kernel<<<dim3(16),       64, 0, stream>>>(swds, wts);
  if (store_gamma) {
    wsum_kernel <<<dim3(64, 16), 256, 0, stream>>>(gamma, wts, out);
  } else {
    hipMemsetAsync(d_out, 0, (size_t)out_size * sizeof(float), stream);
    out_kernel  <<<dim3(16, 4, 16), 256, 0, stream>>>(X, Y, srtu, ziu, srtv, ziv, wts, out);
  }
}

// Round 3
// 317.846 us; speedup vs baseline: 3.6030x; 3.1077x over previous
//
#include <hip/hip_runtime.h>
#include <math.h>

#define INV_TAU 1000.0f   // 1/TAU, TAU=0.001
#define TEMP    0.1f

// Problem: B=2,H=8 -> BH=16; N=256; L=64.  X,Y: [BH,256,64] f32. out: [BH,256,256] f32.
//
// Strategy (round 3): Gamma_l = Pu_l^T Pv_l via MFMA 16x16x32 bf16 with 3-term
// split-bf16 (e = e_hi + e_lo; drop lo*lo ~ 2^-17 rel).  Pass1 dots Gamma tiles
// with cost -> swds (atomicAdd).  Pass2 folds w_l into ziu and accumulates
// sum_l w_l Gamma_l directly in the MFMA accumulator; atomicAdd epilogue (4-way).
// Optional: pass1 stores Gamma as bf16 (134 MB) when ws permits -> pass2 becomes
// a trivial weighted sum (wsum_bf16).
//
// ws layout (float units):
//   cost [16][256][256] @0 (1048576) | srtu @1048576 | ziu | srtv | ziv (262144 ea)
//   swds @2097152 (1024) | wts @2098176 (1024) | gamma_bf16 @2099200 (ushort[16*64*65536])

typedef __attribute__((ext_vector_type(8))) short short8;   // 8 bf16 = 4 VGPRs
typedef __attribute__((ext_vector_type(4))) float f32x4;

__device__ __forceinline__ void bitonic_sort_asc256(float* s, int tid) {
  for (int k = 2; k <= 256; k <<= 1) {
    for (int j = k >> 1; j > 0; j >>= 1) {
      __syncthreads();
      int ixj = tid ^ j;
      if (ixj > tid) {
        float a = s[tid], b = s[ixj];
        bool up = ((tid & k) == 0);
        if (up ? (a > b) : (a < b)) { s[tid] = b; s[ixj] = a; }
      }
    }
  }
  __syncthreads();
}

// K1: cost[bh][j][k] = sqrt(max(|Xj|^2+|Yk|^2-2Xj.Yk, 1e-12))
__global__ __launch_bounds__(256) void cost_kernel(const float* __restrict__ X,
                                                   const float* __restrict__ Y,
                                                   float* __restrict__ cost) {
  const int j = blockIdx.x, bh = blockIdx.y, k = threadIdx.x;
  __shared__ __align__(16) float xr[64];
  if (k < 64) xr[k] = X[((size_t)bh*256 + j)*64 + k];
  __syncthreads();
  const float4* yp = (const float4*)(Y + ((size_t)bh*256 + k)*64);
  const float4* xp = (const float4*)xr;
  float dot = 0.f, x2 = 0.f, y2 = 0.f;
#pragma unroll
  for (int t = 0; t < 16; ++t) {
    float4 yv = yp[t], xv = xp[t];
    dot += xv.x*yv.x + xv.y*yv.y + xv.z*yv.z + xv.w*yv.w;
    x2  += xv.x*xv.x + xv.y*xv.y + xv.z*xv.z + xv.w*xv.w;
    y2  += yv.x*yv.x + yv.y*yv.y + yv.z*yv.z + yv.w*yv.w;
  }
  float c = x2 + y2 - 2.f*dot;
  cost[((size_t)bh*256 + j)*256 + k] = sqrtf(fmaxf(c, 1e-12f));
}

// K2: per (bh,l,uv): descending sort + 1/Z per sorted row (row-max of logits is 0).
__global__ __launch_bounds__(256) void sortz_kernel(const float* __restrict__ X,
                                                    const float* __restrict__ Y,
                                                    float* __restrict__ srtu, float* __restrict__ ziu,
                                                    float* __restrict__ srtv, float* __restrict__ ziv) {
  const int l = blockIdx.x, bh = blockIdx.y, tid = threadIdx.x;
  const float* S = blockIdx.z ? Y : X;
  float* so = blockIdx.z ? srtv : srtu;
  float* zo = blockIdx.z ? ziv  : ziu;
  __shared__ float s[256];
  s[tid] = S[((size_t)bh*256 + tid)*64 + l];
  bitonic_sort_asc256(s, tid);
  float v = s[255 - tid];           // descending
  float z = 0.f;
  for (int jj = 0; jj < 256; ++jj) { float d = s[jj] - v; z += __expf(-d*d*INV_TAU); }
  const int base = (bh*64 + l)*256 + tid;
  so[base] = v; zo[base] = 1.0f / z;
}

// ---- shared device pieces for the MFMA passes ----
#define TPAD 40   // table row stride in shorts (32 data + 8 pad); 80B rows, 16B-aligned

// Stage one 16-entry run: e = exp(-(v-srt_i)^2/tau)*zi_i, split into bf16 hi (RNE) + lo (trunc).
__device__ __forceinline__ void stage_half(float v, int i0, int s0, int r,
                                           const float* __restrict__ srt,
                                           const float* __restrict__ zi,
                                           unsigned short* __restrict__ Th,
                                           unsigned short* __restrict__ Tl) {
  unsigned h[16], lo[16];
#pragma unroll
  for (int ii = 0; ii < 16; ++ii) {
    int i = i0 + s0 + ii;
    float d = v - srt[i];
    float e = __expf(d*d*(-INV_TAU)) * zi[i];
    unsigned u  = __float_as_uint(e);
    unsigned hr = (u + 0x7FFFu + ((u >> 16) & 1u)) & 0xFFFF0000u;   // RNE bf16 (as hi bits)
    h[ii]  = hr >> 16;
    lo[ii] = __float_as_uint(e - __uint_as_float(hr)) >> 16;        // trunc bf16 of residual
  }
  uint4 p;
  p.x = h[0]|(h[1]<<16);  p.y = h[2]|(h[3]<<16);  p.z = h[4]|(h[5]<<16);  p.w = h[6]|(h[7]<<16);
  *(uint4*)&Th[r*TPAD + s0] = p;
  p.x = h[8]|(h[9]<<16);  p.y = h[10]|(h[11]<<16); p.z = h[12]|(h[13]<<16); p.w = h[14]|(h[15]<<16);
  *(uint4*)&Th[r*TPAD + s0 + 8] = p;
  p.x = lo[0]|(lo[1]<<16); p.y = lo[2]|(lo[3]<<16); p.z = lo[4]|(lo[5]<<16); p.w = lo[6]|(lo[7]<<16);
  *(uint4*)&Tl[r*TPAD + s0] = p;
  p.x = lo[8]|(lo[9]<<16); p.y = lo[10]|(lo[11]<<16); p.z = lo[12]|(lo[13]<<16); p.w = lo[14]|(lo[15]<<16);
  *(uint4*)&Tl[r*TPAD + s0 + 8] = p;
}

// 3-split MFMA over one 32-i slab; wave tile 64x64 = 4x4 of 16x16.
// A[m=lane&15][k=q*8+j] from EU^T rows; B[k][n=lane&15] from EV^T rows (verified layouts).
__device__ __forceinline__ void mfma_slab(int lane, int wj, int wk,
                                          const unsigned short* __restrict__ EUh,
                                          const unsigned short* __restrict__ EUl,
                                          const unsigned short* __restrict__ EVh,
                                          const unsigned short* __restrict__ EVl,
                                          f32x4 acc[16]) {
  const int m = lane & 15, co = (lane >> 4) * 8;
  short8 Bh[4], Bl[4];
#pragma unroll
  for (int nt = 0; nt < 4; ++nt) {
    const int row = wk + nt*16 + m;
    Bh[nt] = *(const short8*)&EVh[row*TPAD + co];
    Bl[nt] = *(const short8*)&EVl[row*TPAD + co];
  }
#pragma unroll
  for (int mt = 0; mt < 4; ++mt) {
    const int row = wj + mt*16 + m;
    short8 Ah = *(const short8*)&EUh[row*TPAD + co];
    short8 Al = *(const short8*)&EUl[row*TPAD + co];
#pragma unroll
    for (int nt = 0; nt < 4; ++nt) {
      acc[mt*4+nt] = __builtin_amdgcn_mfma_f32_16x16x32_bf16(Ah, Bh[nt], acc[mt*4+nt], 0, 0, 0);
      acc[mt*4+nt] = __builtin_amdgcn_mfma_f32_16x16x32_bf16(Ah, Bl[nt], acc[mt*4+nt], 0, 0, 0);
      acc[mt*4+nt] = __builtin_amdgcn_mfma_f32_16x16x32_bf16(Al, Bh[nt], acc[mt*4+nt], 0, 0, 0);
    }
  }
}

// Pass 1: per (tile, l, bh): Gamma(128x128 block tile) -> dot with cost -> swds.
// Optionally store Gamma as bf16.
__global__ __launch_bounds__(256, 2) void pass1_kernel(
    const float* __restrict__ X, const float* __restrict__ Y,
    const float* __restrict__ cost,
    const float* __restrict__ srtu, const float* __restrict__ ziu,
    const float* __restrict__ srtv, const float* __restrict__ ziv,
    float* __restrict__ swds, unsigned short* __restrict__ gammah, int store_gamma) {
  const int tile = blockIdx.x, l = blockIdx.y, bh = blockIdx.z;
  const int jb = (tile >> 1) * 128, kb = (tile & 1) * 128;
  const int tid = threadIdx.x, wave = tid >> 6, lane = tid & 63;
  const int wj = (wave >> 1) * 64, wk = (wave & 1) * 64;

  __shared__ float su_loc[128], sv_loc[128];
  __shared__ float srtU[256], ziU[256], srtV[256], ziV[256];
  __shared__ __align__(16) unsigned short EUh[128*TPAD], EUl[128*TPAD],
                                          EVh[128*TPAD], EVl[128*TPAD];
  __shared__ float red[4];

  const int lb = (bh*64 + l)*256;
  if (tid < 128) su_loc[tid]       = X[((size_t)bh*256 + jb + tid)*64 + l];
  else           sv_loc[tid - 128] = Y[((size_t)bh*256 + kb + (tid - 128))*64 + l];
  srtU[tid] = srtu[lb + tid]; ziU[tid] = ziu[lb + tid];
  srtV[tid] = srtv[lb + tid]; ziV[tid] = ziv[lb + tid];

  f32x4 acc[16];
#pragma unroll
  for (int t = 0; t < 16; ++t) acc[t] = (f32x4){0.f, 0.f, 0.f, 0.f};

  const int r  = tid >> 1;
  const int s0 = (tid & 1) * 16;
#pragma unroll 1
  for (int slab = 0; slab < 8; ++slab) {
    __syncthreads();
    stage_half(su_loc[r], slab*32, s0, r, srtU, ziU, EUh, EUl);
    stage_half(sv_loc[r], slab*32, s0, r, srtV, ziV, EVh, EVl);
    __syncthreads();
    mfma_slab(lane, wj, wk, EUh, EUl, EVh, EVl, acc);
  }

  // epilogue: dot with cost; C/D map: col=lane&15, row=(lane>>4)*4+reg
  const float* cb = cost + (size_t)bh * 65536;
  unsigned short* gb = gammah + (((size_t)(bh*64 + l)) << 16);
  const int m = lane & 15, q = lane >> 4;
  float part = 0.f;
#pragma unroll
  for (int mt = 0; mt < 4; ++mt) {
#pragma unroll
    for (int nt = 0; nt < 4; ++nt) {
      const int col  = kb + wk + nt*16 + m;
      const int rowb = jb + wj + mt*16 + q*4;
      f32x4 a = acc[mt*4 + nt];
      part += a.x*cb[(size_t)(rowb+0)*256 + col] + a.y*cb[(size_t)(rowb+1)*256 + col]
            + a.z*cb[(size_t)(rowb+2)*256 + col] + a.w*cb[(size_t)(rowb+3)*256 + col];
      if (store_gamma) {
#pragma unroll
        for (int rr = 0; rr < 4; ++rr) {
          float gv = (rr==0)?a.x:(rr==1)?a.y:(rr==2)?a.z:a.w;
          unsigned u = __float_as_uint(gv);
          gb[(size_t)(rowb+rr)*256 + col] =
              (unsigned short)((u + 0x7FFFu + ((u >> 16) & 1u)) >> 16);
        }
      }
    }
  }
#pragma unroll
  for (int o = 32; o > 0; o >>= 1) part += __shfl_down(part, o, 64);
  if (lane == 0) red[wave] = part;
  __syncthreads();
  if (tid == 0) atomicAdd(&swds[bh*64 + l], red[0] + red[1] + red[2] + red[3]);
}

// K4: weights = softmax(-TEMP*swds) over l
__global__ void weights_kernel(const float* __restrict__ swds, float* __restrict__ weights) {
  const int bh = blockIdx.x, t = threadIdx.x;
  float v = -TEMP * swds[bh*64 + t];
  float m = v;
#pragma unroll
  for (int o = 32; o > 0; o >>= 1) m = fmaxf(m, __shfl_xor(m, o, 64));
  float e = __expf(v - m);
  float ssum = e;
#pragma unroll
  for (int o = 32; o > 0; o >>= 1) ssum += __shfl_xor(ssum, o, 64);
  weights[bh*64 + t] = e / ssum;
}

// Pass 2 (no-gamma-store path): accumulate sum_l w_l Gamma_l directly in MFMA acc.
// grid (tile 0..3, lc 0..3, bh); each block does 16 l's; atomicAdd epilogue (4-way).
__global__ __launch_bounds__(256, 2) void pass2_kernel(
    const float* __restrict__ X, const float* __restrict__ Y,
    const float* __restrict__ srtu, const float* __restrict__ ziu,
    const float* __restrict__ srtv, const float* __restrict__ ziv,
    const float* __restrict__ wts, float* __restrict__ out) {
  const int tile = blockIdx.x, lc = blockIdx.y, bh = blockIdx.z;
  const int jb = (tile >> 1) * 128, kb = (tile & 1) * 128;
  const int tid = threadIdx.x, wave = tid >> 6, lane = tid & 63;
  const int wj = (wave >> 1) * 64, wk = (wave & 1) * 64;

  __shared__ float su_loc[128], sv_loc[128];
  __shared__ float srtU[256], ziU[256], srtV[256], ziV[256];
  __shared__ __align__(16) unsigned short EUh[128*TPAD], EUl[128*TPAD],
                                          EVh[128*TPAD], EVl[128*TPAD];

  f32x4 acc[16];
#pragma unroll
  for (int t = 0; t < 16; ++t) acc[t] = (f32x4){0.f, 0.f, 0.f, 0.f};

  const int r  = tid >> 1;
  const int s0 = (tid & 1) * 16;
#pragma unroll 1
  for (int li = 0; li < 16; ++li) {
    const int l  = lc*16 + li;
    const int lb = (bh*64 + l)*256;
    const float w = wts[bh*64 + l];
    __syncthreads();                 // prev-l table readers done
    if (tid < 128) su_loc[tid]       = X[((size_t)bh*256 + jb + tid)*64 + l];
    else           sv_loc[tid - 128] = Y[((size_t)bh*256 + kb + (tid - 128))*64 + l];
    srtU[tid] = srtu[lb + tid]; ziU[tid] = ziu[lb + tid] * w;   // fold weight into U
    srtV[tid] = srtv[lb + tid]; ziV[tid] = ziv[lb + tid];
#pragma unroll 1
    for (int slab = 0; slab < 8; ++slab) {
      __syncthreads();
      stage_half(su_loc[r], slab*32, s0, r, srtU, ziU, EUh, EUl);
      stage_half(sv_loc[r], slab*32, s0, r, srtV, ziV, EVh, EVl);
      __syncthreads();
      mfma_slab(lane, wj, wk, EUh, EUl, EVh, EVl, acc);
    }
  }
  float* ob = out + (size_t)bh * 65536;
  const int m = lane & 15, q = lane >> 4;
#pragma unroll
  for (int mt = 0; mt < 4; ++mt) {
#pragma unroll
    for (int nt = 0; nt < 4; ++nt) {
      const int col  = kb + wk + nt*16 + m;
      const int rowb = jb + wj + mt*16 + q*4;
      f32x4 a = acc[mt*4 + nt];
      atomicAdd(&ob[(size_t)(rowb+0)*256 + col], a.x);
      atomicAdd(&ob[(size_t)(rowb+1)*256 + col], a.y);
      atomicAdd(&ob[(size_t)(rowb+2)*256 + col], a.z);
      atomicAdd(&ob[(size_t)(rowb+3)*256 + col], a.w);
    }
  }
}

// Pass 2 (gamma-store path): out = sum_l w_l * Gamma_bf16_l
__global__ __launch_bounds__(256) void wsum_bf16(const unsigned short* __restrict__ g,
                                                 const float* __restrict__ wts,
                                                 float* __restrict__ out) {
  const int bh = blockIdx.y;
  const size_t p = ((size_t)blockIdx.x * 256 + threadIdx.x) * 4;
  __shared__ float w[64];
  if (threadIdx.x < 64) w[threadIdx.x] = wts[bh*64 + threadIdx.x];
  __syncthreads();
  const unsigned short* gb = g + (((size_t)bh * 64) << 16) + p;
  float4 acc = {0.f, 0.f, 0.f, 0.f};
#pragma unroll 4
  for (int l = 0; l < 64; ++l) {
    uint2 pk = *(const uint2*)&gb[(size_t)l << 16];
    float wl = w[l];
    acc.x += wl * __uint_as_float(pk.x << 16);
    acc.y += wl * __uint_as_float(pk.x & 0xFFFF0000u);
    acc.z += wl * __uint_as_float(pk.y << 16);
    acc.w += wl * __uint_as_float(pk.y & 0xFFFF0000u);
  }
  *(float4*)&out[((size_t)bh << 16) + p] = acc;
}

extern "C" void kernel_launch(void* const* d_in, const int* in_sizes, int n_in,
                              void* d_out, int out_size, void* d_ws, size_t ws_size,
                              hipStream_t stream) {
  (void)in_sizes; (void)n_in;
  const float* X = (const float*)d_in[0];
  const float* Y = (const float*)d_in[1];
  float* out = (float*)d_out;
  float* ws  = (float*)d_ws;
  float* cost  = ws;                    // 1048576
  float* srtu  = ws   + 1048576;
  float* ziu   = srtu + 262144;
  float* srtv  = ziu  + 262144;
  float* ziv   = srtv + 262144;
  float* swds  = ziv  + 262144;         // 1024
  float* wts   = swds + 1024;           // 1024
  unsigned short* gammah = (unsigned short*)(wts + 1024);   // 67108864 ushorts = 134 MB

  const size_t need_bytes = (size_t)2099200 * 4 + (size_t)67108864 * 2;
  const int store_gamma = (ws_size >= need_bytes) ? 1 : 0;  // constant -> graph-safe

  hipMemsetAsync(swds, 0, 1024 * sizeof(float), stream);
  hipMemsetAsync(d_out, 0, (size_t)out_size * sizeof(float), stream);
  cost_kernel   <<<dim3(256, 16),   256, 0, stream>>>(X, Y, cost);
  sortz_kernel  <<<dim3(64, 16, 2), 256, 0, stream>>>(X, Y, srtu, ziu, srtv, ziv);
  pass1_kernel  <<<dim3(4, 64, 16), 256, 0, stream>>>(X, Y, cost, srtu, ziu, srtv, ziv,
                                                      swds, gammah, store_gamma);
  weights_kernel<<<dim3(16),         64, 0, stream>>>(swds, wts);
  if (store_gamma) {
    wsum_bf16   <<<dim3(64, 16),    256, 0, stream>>>(gammah, wts, out);
  } else {
    pass2_kernel<<<dim3(4, 4, 16),  256, 0, stream>>>(X, Y, srtu, ziu, srtv, ziv, wts, out);
  }
}

// Round 4
// 283.738 us; speedup vs baseline: 4.0361x; 1.1202x over previous
//
#include <hip/hip_runtime.h>
#include <math.h>

#define INV_TAU 1000.0f
#define TEMP    0.1f
#define CEXP    -1442.6950408889634f   // -1000 * log2(e)

// Problem: B=2,H=8 -> BH=16; N=256; L=64.  X,Y: [BH,256,64] f32. out: [BH,256,256] f32.
//
// Round 4: single-fp16 MFMA (error ~2^-11 rel on Gamma; delta-swds ~0.02 abs ->
// ~0.2% weight noise -> ~2e-4 out error, inside threshold). exp2-folded staging
// (4 VALU/entry + pkrtz pack), strip blocks 128jx256k (staging redundancy 1.5x
// not 2x), swizzled 64B-row tables (conflict-free frag reads).
//
// ws (floats): cost[16*65536] | srtu | lziu | srtv | lziv (262144 ea) |
//              swds[1024] | wts[1024] | gamma bf16 ushort[16*64*65536]

typedef __attribute__((ext_vector_type(8))) _Float16 half8;
typedef __attribute__((ext_vector_type(2))) _Float16 half2_t;
typedef __attribute__((ext_vector_type(8))) short short8;
typedef __attribute__((ext_vector_type(4))) float f32x4;

__device__ __forceinline__ float fexp2(float x) { return __builtin_amdgcn_exp2f(x); }

__device__ __forceinline__ half8 ldsh8(const unsigned short* p) {
  return __builtin_bit_cast(half8, *(const short8*)p);
}

// swizzled short-offset of (row, group g of 8 i's) in a 32-short-per-row table
__device__ __forceinline__ int tswz(int row, int g) {
  return row * 32 + (((g + (row >> 1)) & 3) << 3);
}

__device__ __forceinline__ void bitonic_sort_asc256(float* s, int tid) {
  for (int k = 2; k <= 256; k <<= 1) {
    for (int j = k >> 1; j > 0; j >>= 1) {
      __syncthreads();
      int ixj = tid ^ j;
      if (ixj > tid) {
        float a = s[tid], b = s[ixj];
        bool up = ((tid & k) == 0);
        if (up ? (a > b) : (a < b)) { s[tid] = b; s[ixj] = a; }
      }
    }
  }
  __syncthreads();
}

// K1: cost[bh][j][k] = sqrt(max(|Xj|^2+|Yk|^2-2Xj.Yk, 1e-12))
__global__ __launch_bounds__(256) void cost_kernel(const float* __restrict__ X,
                                                   const float* __restrict__ Y,
                                                   float* __restrict__ cost) {
  const int j = blockIdx.x, bh = blockIdx.y, k = threadIdx.x;
  __shared__ __align__(16) float xr[64];
  if (k < 64) xr[k] = X[((size_t)bh*256 + j)*64 + k];
  __syncthreads();
  const float4* yp = (const float4*)(Y + ((size_t)bh*256 + k)*64);
  const float4* xp = (const float4*)xr;
  float dot = 0.f, x2 = 0.f, y2 = 0.f;
#pragma unroll
  for (int t = 0; t < 16; ++t) {
    float4 yv = yp[t], xv = xp[t];
    dot += xv.x*yv.x + xv.y*yv.y + xv.z*yv.z + xv.w*yv.w;
    x2  += xv.x*xv.x + xv.y*xv.y + xv.z*xv.z + xv.w*xv.w;
    y2  += yv.x*yv.x + yv.y*yv.y + yv.z*yv.z + yv.w*yv.w;
  }
  float c = x2 + y2 - 2.f*dot;
  cost[((size_t)bh*256 + j)*256 + k] = sqrtf(fmaxf(c, 1e-12f));
}

// K2: descending sort + lzi = -log2(Z) per sorted row (row max of logits is 0).
__global__ __launch_bounds__(256) void sortz_kernel(const float* __restrict__ X,
                                                    const float* __restrict__ Y,
                                                    float* __restrict__ srtu, float* __restrict__ lziu,
                                                    float* __restrict__ srtv, float* __restrict__ lziv) {
  const int l = blockIdx.x, bh = blockIdx.y, tid = threadIdx.x;
  const float* S = blockIdx.z ? Y : X;
  float* so = blockIdx.z ? srtv : srtu;
  float* zo = blockIdx.z ? lziv : lziu;
  __shared__ float s[256];
  s[tid] = S[((size_t)bh*256 + tid)*64 + l];
  bitonic_sort_asc256(s, tid);
  float v = s[255 - tid];
  float z = 0.f;
  for (int jj = 0; jj < 256; ++jj) { float d = s[jj] - v; z += __expf(-d*d*INV_TAU); }
  const int base = (bh*64 + l)*256 + tid;
  so[base] = v; zo[base] = -__log2f(z);
}

// ---- staging: one 32-i slab of the fp16 exp tables (swizzled layout) ----
// EU: 128 rows; thread t -> row t&127, group-pair (t>>7)*2.
// EV: 256 rows; thread t -> rows (t&127), (t&127)+128, group-pair (t>>7)*2.
__device__ __forceinline__ void stage_slab(int t, int ib,
                                           const float* __restrict__ su, const float* __restrict__ sv,
                                           const float* __restrict__ srtU, const float* __restrict__ lziU,
                                           const float* __restrict__ srtV, const float* __restrict__ lziV,
                                           unsigned short* __restrict__ EU,
                                           unsigned short* __restrict__ EV) {
  const int r  = t & 127;
  const int gp = (t >> 7) << 1;               // group-pair base: 0 or 2
  const int i0 = ib + (gp << 3);              // 16 consecutive i's
  // EU
  {
    float v = su[r];
    float e[16];
#pragma unroll
    for (int ii = 0; ii < 16; ++ii) {
      float d = v - srtU[i0 + ii];
      e[ii] = fexp2(fmaf(d*d, CEXP, lziU[i0 + ii]));
    }
#pragma unroll
    for (int gg = 0; gg < 2; ++gg) {
      uint4 w;
      w.x = __builtin_bit_cast(unsigned, __builtin_amdgcn_cvt_pkrtz(e[gg*8+0], e[gg*8+1]));
      w.y = __builtin_bit_cast(unsigned, __builtin_amdgcn_cvt_pkrtz(e[gg*8+2], e[gg*8+3]));
      w.z = __builtin_bit_cast(unsigned, __builtin_amdgcn_cvt_pkrtz(e[gg*8+4], e[gg*8+5]));
      w.w = __builtin_bit_cast(unsigned, __builtin_amdgcn_cvt_pkrtz(e[gg*8+6], e[gg*8+7]));
      *(uint4*)&EU[tswz(r, gp + gg)] = w;
    }
  }
  // EV (rows r and r+128 keep the write windows uniformly spread)
#pragma unroll
  for (int rr = 0; rr < 2; ++rr) {
    const int row = r + rr*128;
    float v = sv[row];
    float e[16];
#pragma unroll
    for (int ii = 0; ii < 16; ++ii) {
      float d = v - srtV[i0 + ii];
      e[ii] = fexp2(fmaf(d*d, CEXP, lziV[i0 + ii]));
    }
#pragma unroll
    for (int gg = 0; gg < 2; ++gg) {
      uint4 w;
      w.x = __builtin_bit_cast(unsigned, __builtin_amdgcn_cvt_pkrtz(e[gg*8+0], e[gg*8+1]));
      w.y = __builtin_bit_cast(unsigned, __builtin_amdgcn_cvt_pkrtz(e[gg*8+2], e[gg*8+3]));
      w.z = __builtin_bit_cast(unsigned, __builtin_amdgcn_cvt_pkrtz(e[gg*8+4], e[gg*8+5]));
      w.w = __builtin_bit_cast(unsigned, __builtin_amdgcn_cvt_pkrtz(e[gg*8+6], e[gg*8+7]));
      *(uint4*)&EV[tswz(row, gp + gg)] = w;
    }
  }
}

// Pass 1: per (strip sb, l, bh): Gamma strip (128j x 256k) = Pu^T Pv via one
// fp16 MFMA per frag pair; dot with cost -> swds; store Gamma bf16.
__global__ __launch_bounds__(256, 2) void pass1_kernel(
    const float* __restrict__ X, const float* __restrict__ Y,
    const float* __restrict__ cost,
    const float* __restrict__ srtu, const float* __restrict__ lziu,
    const float* __restrict__ srtv, const float* __restrict__ lziv,
    float* __restrict__ swds, unsigned short* __restrict__ gammah, int store_gamma) {
  const int sb = blockIdx.x, l = blockIdx.y, bh = blockIdx.z;
  const int j0 = sb * 128;
  const int tid = threadIdx.x, wave = tid >> 6, lane = tid & 63;
  const int wj = (wave & 1) * 64, wk = (wave >> 1) * 128;
  const int m = lane & 15, q = lane >> 4;
  const int inner = m*32 + (((q + (m >> 1)) & 3) << 3);

  __shared__ float su[128], sv[256];
  __shared__ float srtU[256], lziU[256], srtV[256], lziV[256];
  __shared__ __align__(16) unsigned short EU[128*32];
  __shared__ __align__(16) unsigned short EV[256*32];
  __shared__ float red[4];

  const int lb = (bh*64 + l)*256;
  if (tid < 128) su[tid] = X[((size_t)bh*256 + j0 + tid)*64 + l];
  sv[tid]   = Y[((size_t)bh*256 + tid)*64 + l];
  srtU[tid] = srtu[lb + tid]; lziU[tid] = lziu[lb + tid];
  srtV[tid] = srtv[lb + tid]; lziV[tid] = lziv[lb + tid];

  f32x4 acc[32];
#pragma unroll
  for (int t = 0; t < 32; ++t) acc[t] = (f32x4){0.f, 0.f, 0.f, 0.f};

#pragma unroll 1
  for (int slab = 0; slab < 8; ++slab) {
    __syncthreads();
    stage_slab(tid, slab*32, su, sv, srtU, lziU, srtV, lziV, EU, EV);
    __syncthreads();
    half8 B[8];
#pragma unroll
    for (int nt = 0; nt < 8; ++nt) B[nt] = ldsh8(&EV[(wk + nt*16)*32 + inner]);
#pragma unroll
    for (int mt = 0; mt < 4; ++mt) {
      half8 A = ldsh8(&EU[(wj + mt*16)*32 + inner]);
#pragma unroll
      for (int nt = 0; nt < 8; ++nt)
        acc[mt*8+nt] = __builtin_amdgcn_mfma_f32_16x16x32_f16(A, B[nt], acc[mt*8+nt], 0, 0, 0);
    }
  }

  // epilogue: C/D map col=lane&15, row=(lane>>4)*4+reg
  const float* cb = cost + (size_t)bh * 65536;
  unsigned short* gb = gammah + (((size_t)(bh*64 + l)) << 16);
  float part = 0.f;
#pragma unroll
  for (int mt = 0; mt < 4; ++mt) {
#pragma unroll
    for (int nt = 0; nt < 8; ++nt) {
      const int col  = wk + nt*16 + m;
      const int rowb = j0 + wj + mt*16 + q*4;
      f32x4 a = acc[mt*8 + nt];
      part += a.x*cb[(size_t)(rowb+0)*256 + col] + a.y*cb[(size_t)(rowb+1)*256 + col]
            + a.z*cb[(size_t)(rowb+2)*256 + col] + a.w*cb[(size_t)(rowb+3)*256 + col];
      if (store_gamma) {
#pragma unroll
        for (int rr = 0; rr < 4; ++rr) {
          float gv = (rr==0)?a.x:(rr==1)?a.y:(rr==2)?a.z:a.w;
          unsigned u = __float_as_uint(gv);
          gb[(size_t)(rowb+rr)*256 + col] =
              (unsigned short)((u + 0x7FFFu + ((u >> 16) & 1u)) >> 16);  // bf16 RNE
        }
      }
    }
  }
#pragma unroll
  for (int o = 32; o > 0; o >>= 1) part += __shfl_down(part, o, 64);
  if (lane == 0) red[wave] = part;
  __syncthreads();
  if (tid == 0) atomicAdd(&swds[bh*64 + l], red[0] + red[1] + red[2] + red[3]);
}

// K4: weights = softmax(-TEMP*swds) over l
__global__ void weights_kernel(const float* __restrict__ swds, float* __restrict__ weights) {
  const int bh = blockIdx.x, t = threadIdx.x;
  float v = -TEMP * swds[bh*64 + t];
  float m = v;
#pragma unroll
  for (int o = 32; o > 0; o >>= 1) m = fmaxf(m, __shfl_xor(m, o, 64));
  float e = __expf(v - m);
  float ssum = e;
#pragma unroll
  for (int o = 32; o > 0; o >>= 1) ssum += __shfl_xor(ssum, o, 64);
  weights[bh*64 + t] = e / ssum;
}

// Pass 2 (gamma path): out = sum_l w_l * Gamma_bf16_l  (HBM-streaming)
__global__ __launch_bounds__(256) void wsum_bf16(const unsigned short* __restrict__ g,
                                                 const float* __restrict__ wts,
                                                 float* __restrict__ out) {
  const int bh = blockIdx.y;
  const size_t p = ((size_t)blockIdx.x * 256 + threadIdx.x) * 4;
  __shared__ float w[64];
  if (threadIdx.x < 64) w[threadIdx.x] = wts[bh*64 + threadIdx.x];
  __syncthreads();
  const unsigned short* gb = g + (((size_t)bh * 64) << 16) + p;
  float4 acc = {0.f, 0.f, 0.f, 0.f};
#pragma unroll 4
  for (int l = 0; l < 64; ++l) {
    uint2 pk = *(const uint2*)&gb[(size_t)l << 16];
    float wl = w[l];
    acc.x += wl * __uint_as_float(pk.x << 16);
    acc.y += wl * __uint_as_float(pk.x & 0xFFFF0000u);
    acc.z += wl * __uint_as_float(pk.y << 16);
    acc.w += wl * __uint_as_float(pk.y & 0xFFFF0000u);
  }
  *(float4*)&out[((size_t)bh << 16) + p] = acc;
}

// Pass 2 fallback (ws too small for gamma): recompute with w folded via log2.
__global__ __launch_bounds__(256, 2) void pass2_kernel(
    const float* __restrict__ X, const float* __restrict__ Y,
    const float* __restrict__ srtu, const float* __restrict__ lziu,
    const float* __restrict__ srtv, const float* __restrict__ lziv,
    const float* __restrict__ wts, float* __restrict__ out) {
  const int sb = blockIdx.x, lc = blockIdx.y, bh = blockIdx.z;
  const int j0 = sb * 128;
  const int tid = threadIdx.x, wave = tid >> 6, lane = tid & 63;
  const int wj = (wave & 1) * 64, wk = (wave >> 1) * 128;
  const int m = lane & 15, q = lane >> 4;
  const int inner = m*32 + (((q + (m >> 1)) & 3) << 3);

  __shared__ float su[128], sv[256];
  __shared__ float srtU[256], lziU[256], srtV[256], lziV[256];
  __shared__ __align__(16) unsigned short EU[128*32];
  __shared__ __align__(16) unsigned short EV[256*32];

  f32x4 acc[32];
#pragma unroll
  for (int t = 0; t < 32; ++t) acc[t] = (f32x4){0.f, 0.f, 0.f, 0.f};

#pragma unroll 1
  for (int li = 0; li < 16; ++li) {
    const int l  = lc*16 + li;
    const int lb = (bh*64 + l)*256;
    const float lw = __log2f(wts[bh*64 + l]);
    __syncthreads();
    if (tid < 128) su[tid] = X[((size_t)bh*256 + j0 + tid)*64 + l];
    sv[tid]   = Y[((size_t)bh*256 + tid)*64 + l];
    srtU[tid] = srtu[lb + tid]; lziU[tid] = lziu[lb + tid] + lw;
    srtV[tid] = srtv[lb + tid]; lziV[tid] = lziv[lb + tid];
#pragma unroll 1
    for (int slab = 0; slab < 8; ++slab) {
      __syncthreads();
      stage_slab(tid, slab*32, su, sv, srtU, lziU, srtV, lziV, EU, EV);
      __syncthreads();
      half8 B[8];
#pragma unroll
      for (int nt = 0; nt < 8; ++nt) B[nt] = ldsh8(&EV[(wk + nt*16)*32 + inner]);
#pragma unroll
      for (int mt = 0; mt < 4; ++mt) {
        half8 A = ldsh8(&EU[(wj + mt*16)*32 + inner]);
#pragma unroll
        for (int nt = 0; nt < 8; ++nt)
          acc[mt*8+nt] = __builtin_amdgcn_mfma_f32_16x16x32_f16(A, B[nt], acc[mt*8+nt], 0, 0, 0);
      }
    }
  }
  float* ob = out + (size_t)bh * 65536;
#pragma unroll
  for (int mt = 0; mt < 4; ++mt) {
#pragma unroll
    for (int nt = 0; nt < 8; ++nt) {
      const int col  = wk + nt*16 + m;
      const int rowb = j0 + wj + mt*16 + q*4;
      f32x4 a = acc[mt*8 + nt];
      atomicAdd(&ob[(size_t)(rowb+0)*256 + col], a.x);
      atomicAdd(&ob[(size_t)(rowb+1)*256 + col], a.y);
      atomicAdd(&ob[(size_t)(rowb+2)*256 + col], a.z);
      atomicAdd(&ob[(size_t)(rowb+3)*256 + col], a.w);
    }
  }
}

extern "C" void kernel_launch(void* const* d_in, const int* in_sizes, int n_in,
                              void* d_out, int out_size, void* d_ws, size_t ws_size,
                              hipStream_t stream) {
  (void)in_sizes; (void)n_in;
  const float* X = (const float*)d_in[0];
  const float* Y = (const float*)d_in[1];
  float* out = (float*)d_out;
  float* ws  = (float*)d_ws;
  float* cost  = ws;                    // 1048576
  float* srtu  = ws   + 1048576;
  float* lziu  = srtu + 262144;
  float* srtv  = lziu + 262144;
  float* lziv  = srtv + 262144;
  float* swds  = lziv + 262144;         // 1024
  float* wts   = swds + 1024;           // 1024
  unsigned short* gammah = (unsigned short*)(wts + 1024);   // 67108864 ushorts

  const size_t need_bytes = (size_t)2099200 * 4 + (size_t)67108864 * 2;
  const int store_gamma = (ws_size >= need_bytes) ? 1 : 0;  // constant -> graph-safe

  hipMemsetAsync(swds, 0, 1024 * sizeof(float), stream);
  cost_kernel   <<<dim3(256, 16),   256, 0, stream>>>(X, Y, cost);
  sortz_kernel  <<<dim3(64, 16, 2), 256, 0, stream>>>(X, Y, srtu, lziu, srtv, lziv);
  pass1_kernel  <<<dim3(2, 64, 16), 256, 0, stream>>>(X, Y, cost, srtu, lziu, srtv, lziv,
                                                      swds, gammah, store_gamma);
  weights_kernel<<<dim3(16),         64, 0, stream>>>(swds, wts);
  if (store_gamma) {
    wsum_bf16   <<<dim3(64, 16),    256, 0, stream>>>(gammah, wts, out);
  } else {
    hipMemsetAsync(d_out, 0, (size_t)out_size * sizeof(float), stream);
    pass2_kernel<<<dim3(2, 4, 16),  256, 0, stream>>>(X, Y, srtu, lziu, srtv, lziv, wts, out);
  }
}